// Round 8
// baseline (262.279 us; speedup 1.0000x reference)
//
#include <hip/hip_runtime.h>
#include <hip/hip_bf16.h>

#define NN 50000
#define EE 1600000

__device__ __forceinline__ float bflo(unsigned u) { return __uint_as_float(u << 16); }
__device__ __forceinline__ float bfhi(unsigned u) { return __uint_as_float(u & 0xffff0000u); }

// ---------------- K1: h = elu(x) @ W (stored bf16-packed) ; a_src/a_dst ----------------
// block 256 = 4 waves, 64 rows/block. Lane = rs*32+c: cols {2c,2c+1}, rows
// rbase..rbase+7. Per 4 k-steps: 4 b64 (W) + 8 b128 (xs) feed 64 FMAs (~FMA-bound).
__global__ __launch_bounds__(256) void k_proj(
    const float* __restrict__ x, const float* __restrict__ W,
    const float* __restrict__ att_src, const float* __restrict__ att_dst,
    unsigned* __restrict__ h2u, float* __restrict__ a_src, float* __restrict__ a_dst) {
  __shared__ float Wl[128 * 64];   // [k][c] row-major, 32 KB
  __shared__ float xs[64 * 132];   // 64 rows, stride 132 (16B-aligned rows), 33 KB
  int tid = threadIdx.x;
  int row0 = blockIdx.x * 64;
  for (int i = tid; i < 128 * 64; i += 256) Wl[i] = W[i];
  for (int i = tid; i < 64 * 128; i += 256) {
    int r = i >> 7, k = i & 127;
    int row = row0 + r;
    float v = (row < NN) ? x[row * 128 + k] : 0.f;
    xs[r * 132 + k] = v > 0.f ? v : (__expf(v) - 1.f);   // ELU
  }
  __syncthreads();
  int w = tid >> 6, lane = tid & 63;
  int rs = lane >> 5, c = lane & 31;
  int rbase = w * 16 + rs * 8;               // block-local rows rbase..rbase+7
  float a0[8] = {0, 0, 0, 0, 0, 0, 0, 0}, a1[8] = {0, 0, 0, 0, 0, 0, 0, 0};
  const float2* W2 = (const float2*)Wl;
  for (int k4 = 0; k4 < 128; k4 += 4) {
    float2 wv0 = W2[(k4 + 0) * 32 + c];
    float2 wv1 = W2[(k4 + 1) * 32 + c];
    float2 wv2 = W2[(k4 + 2) * 32 + c];
    float2 wv3 = W2[(k4 + 3) * 32 + c];
#pragma unroll
    for (int j = 0; j < 8; ++j) {
      float4 xv = *(const float4*)&xs[(rbase + j) * 132 + k4];
      a0[j] += xv.x * wv0.x + xv.y * wv1.x + xv.z * wv2.x + xv.w * wv3.x;
      a1[j] += xv.x * wv0.y + xv.y * wv1.y + xv.z * wv2.y + xv.w * wv3.y;
    }
  }
  int hh = c >> 4;
  float2 av_s = ((const float2*)att_src)[c];  // cols 2c,2c+1 of flat [2][32]
  float2 av_d = ((const float2*)att_dst)[c];
#pragma unroll
  for (int j = 0; j < 8; ++j) {
    int row = row0 + rbase + j;
    bool ok = row < NN;
    if (ok) {
      unsigned lo = (unsigned)__bfloat16_as_ushort(__float2bfloat16(a0[j]));
      unsigned hi = (unsigned)__bfloat16_as_ushort(__float2bfloat16(a1[j]));
      h2u[row * 32 + c] = lo | (hi << 16);
    }
    float ps = a0[j] * av_s.x + a1[j] * av_s.y;
    float pd = a0[j] * av_d.x + a1[j] * av_d.y;
#pragma unroll
    for (int o = 1; o < 16; o <<= 1) {        // reduce 16 lanes of this head group
      ps += __shfl_xor(ps, o);
      pd += __shfl_xor(pd, o);
    }
    if (ok && (c & 15) == 0) { a_src[row * 2 + hh] = ps; a_dst[row * 2 + hh] = pd; }
  }
}

// ---------------- K2: build 16 linked sublists/node + per-edge softmax weights ----------------
// One lane per edge: gathers two 8 B attention entries (L2-resident 800 KB),
// computes both heads' exp once, writes a 16 B record. A node's 16 head slots
// are exactly one 64 B line -> atomicExch locality.
__global__ __launch_bounds__(256) void k_build(
    const int* __restrict__ src, const int* __restrict__ dst,
    const float2* __restrict__ a_src2, const float2* __restrict__ a_dst2,
    int* __restrict__ head16, int4* __restrict__ edge4) {
  int e = blockIdx.x * 256 + threadIdx.x;
  int s = src[e], d = dst[e];
  float2 as = a_src2[s], ad = a_dst2[d];
  float l0 = as.x + ad.x; l0 = fmaxf(l0, 0.2f * l0);
  float l1 = as.y + ad.y; l1 = fmaxf(l1, 0.2f * l1);
  int old = atomicExch(&head16[d * 16 + (e & 15)], e);
  edge4[e] = make_int4(s, old, __float_as_int(__expf(l0)), __float_as_int(__expf(l1)));
}

// ---------------- K3: weighted aggregate (weights precomputed) ----------------
// one wave per dst node; each 16-lane quarter chases 4 chains (16 chains/node
// of mean length 2 -> 16-deep memory-level parallelism). Lane owns 4 cols
// (cols 4c..4c+3, one uint2 h-load per record). Quarters merged via shfl_xor.
__global__ __launch_bounds__(256) void k_agg(
    const unsigned* __restrict__ h2u, const float* __restrict__ a_src,
    const float* __restrict__ a_dst, const int* __restrict__ head16,
    const int4* __restrict__ edge4, const float* __restrict__ bias,
    float* __restrict__ out) {
  int n = blockIdx.x * 4 + (threadIdx.x >> 6);
  int lane = threadIdx.x & 63;
  int c = lane & 15;           // col quad: cols 4c..4c+3
  int q = lane >> 4;           // quarter-wave id
  int hh = c >> 3;             // head of this col quad

  float denom = 0.f, A0 = 0.f, A1 = 0.f, A2 = 0.f, A3 = 0.f;
  if (q == 0) {                // self loop (PyG add_self_loops), counted once
    float l0 = a_src[n * 2 + hh] + a_dst[n * 2 + hh];
    l0 = fmaxf(l0, 0.2f * l0);
    float es = __expf(l0);
    uint2 hv = *(const uint2*)&h2u[n * 32 + 2 * c];
    denom = es;
    A0 = es * bflo(hv.x); A1 = es * bfhi(hv.x);
    A2 = es * bflo(hv.y); A3 = es * bfhi(hv.y);
  }

  int e0 = head16[n * 16 + q * 4 + 0];
  int e1 = head16[n * 16 + q * 4 + 1];
  int e2 = head16[n * 16 + q * 4 + 2];
  int e3 = head16[n * 16 + q * 4 + 3];
  while (__any(max(max(e0, e1), max(e2, e3)) >= 0)) {
    int4 p0 = edge4[max(e0, 0)];
    int4 p1 = edge4[max(e1, 0)];
    int4 p2 = edge4[max(e2, 0)];
    int4 p3 = edge4[max(e3, 0)];
    uint2 h0 = *(const uint2*)&h2u[p0.x * 32 + 2 * c];
    uint2 h1 = *(const uint2*)&h2u[p1.x * 32 + 2 * c];
    uint2 h2 = *(const uint2*)&h2u[p2.x * 32 + 2 * c];
    uint2 h3 = *(const uint2*)&h2u[p3.x * 32 + 2 * c];
    float x0 = (e0 >= 0) ? __int_as_float(hh ? p0.w : p0.z) : 0.f;
    float x1 = (e1 >= 0) ? __int_as_float(hh ? p1.w : p1.z) : 0.f;
    float x2 = (e2 >= 0) ? __int_as_float(hh ? p2.w : p2.z) : 0.f;
    float x3 = (e3 >= 0) ? __int_as_float(hh ? p3.w : p3.z) : 0.f;
    denom += (x0 + x1) + (x2 + x3);
    A0 += x0 * bflo(h0.x) + x1 * bflo(h1.x) + x2 * bflo(h2.x) + x3 * bflo(h3.x);
    A1 += x0 * bfhi(h0.x) + x1 * bfhi(h1.x) + x2 * bfhi(h2.x) + x3 * bfhi(h3.x);
    A2 += x0 * bflo(h0.y) + x1 * bflo(h1.y) + x2 * bflo(h2.y) + x3 * bflo(h3.y);
    A3 += x0 * bfhi(h0.y) + x1 * bfhi(h1.y) + x2 * bfhi(h2.y) + x3 * bfhi(h3.y);
    e0 = (e0 >= 0) ? p0.y : -1;
    e1 = (e1 >= 0) ? p1.y : -1;
    e2 = (e2 >= 0) ? p2.y : -1;
    e3 = (e3 >= 0) ? p3.y : -1;
  }
  // merge quarters: q0+=q1 (xor 16), then +=q2/q3 (xor 32)
  denom += __shfl_xor(denom, 16); A0 += __shfl_xor(A0, 16);
  A1 += __shfl_xor(A1, 16); A2 += __shfl_xor(A2, 16); A3 += __shfl_xor(A3, 16);
  denom += __shfl_xor(denom, 32); A0 += __shfl_xor(A0, 32);
  A1 += __shfl_xor(A1, 32); A2 += __shfl_xor(A2, 32); A3 += __shfl_xor(A3, 32);
  if (q == 0) {
    float inv = 1.f / (denom + 1e-16f);
    float4 b = ((const float4*)bias)[c];
    ((float4*)out)[n * 16 + c] =
        make_float4(A0 * inv + b.x, A1 * inv + b.y, A2 * inv + b.z, A3 * inv + b.w);
  }
}

extern "C" void kernel_launch(void* const* d_in, const int* in_sizes, int n_in,
                              void* d_out, int out_size, void* d_ws, size_t ws_size,
                              hipStream_t stream) {
  const float* x       = (const float*)d_in[0];
  const float* W       = (const float*)d_in[1];
  const float* att_src = (const float*)d_in[2];
  const float* att_dst = (const float*)d_in[3];
  const float* bias    = (const float*)d_in[4];
  const int* edge_index = (const int*)d_in[5];
  const int* esrc = edge_index;        // edge_index[0, :]
  const int* edst = edge_index + EE;   // edge_index[1, :]

  // Workspace layout (a_src/a_dst are 100K floats = 400,000 B EACH):
  char* base = (char*)d_ws;
  unsigned* h2u  = (unsigned*)base;                      // [0     .. 6.4M)   h bf16x2
  float* a_src_b = (float*)(base + 6400000);             // [6.4M  .. 6.8M)
  float* a_dst_b = (float*)(base + 6800000);             // [6.8M  .. 7.2M)
  int*   head16  = (int*)(base + 7200000);               // [7.2M  .. 10.4M)  800K i32
  int4*  edge4   = (int4*)(base + 10400000);             // [10.4M .. 36.0M)  1.6M int4

  hipMemsetAsync(head16, 0xFF, 800000 * sizeof(int), stream);  // -1 sentinels
  k_proj<<<(NN + 63) / 64, 256, 0, stream>>>(x, W, att_src, att_dst, h2u,
                                             a_src_b, a_dst_b);
  k_build<<<EE / 256, 256, 0, stream>>>(esrc, edst, (const float2*)a_src_b,
                                        (const float2*)a_dst_b, head16, edge4);
  k_agg<<<NN / 4, 256, 0, stream>>>(h2u, a_src_b, a_dst_b, head16, edge4, bias,
                                    (float*)d_out);
}